// Round 20
// baseline (115.582 us; speedup 1.0000x reference)
//
#include <hip/hip_runtime.h>
#include <hip/hip_bf16.h>

// Problem constants (MultiHeadAttention, B=2, S=2048, D=1024, H=16)
#define B_SZ    2
#define S_LEN   2048
#define D_MODEL 1024
#define H_NUM   16
#define DH      64
#define M_TOT   (B_SZ * S_LEN)   // 4096 tokens

// scale = S^-0.5 (faithful bug) folded with log2(e) for exp2-domain softmax
#define QSCALE (0.022097086912079608f * 1.4426950408889634f)

typedef __attribute__((ext_vector_type(8)))  short          bf16x8;
typedef __attribute__((ext_vector_type(4)))  float          f32x4;
typedef __attribute__((ext_vector_type(16))) float          f32x16;
typedef __attribute__((ext_vector_type(8)))  unsigned short u16x8;
typedef __attribute__((ext_vector_type(4)))  unsigned short u16x4;

__device__ inline unsigned short f2bf(float f) {
  unsigned int u = __float_as_uint(f);
  u += 0x7fffu + ((u >> 16) & 1u);   // RNE (no NaN inputs here)
  return (unsigned short)(u >> 16);
}

__device__ inline float bf2f(unsigned short u) {
  return __uint_as_float(((unsigned)u) << 16);
}

__device__ inline float fexp2(float x) {
#if __has_builtin(__builtin_amdgcn_exp2f)
  return __builtin_amdgcn_exp2f(x);
#else
  return exp2f(x);
#endif
}

__device__ inline unsigned cvt_pk_bf16(float lo, float hi) {
  unsigned r;
  asm("v_cvt_pk_bf16_f32 %0, %1, %2" : "=v"(r) : "v"(lo), "v"(hi));
  return r;
}

// async global->LDS, 16B per lane. LDS dest = wave-uniform base + lane*16.
__device__ inline void gload16(const void* g, void* l) {
  __builtin_amdgcn_global_load_lds(
      (const __attribute__((address_space(1))) void*)g,
      (__attribute__((address_space(3))) void*)l, 16, 0, 0);
}

// ---------------------------------------------------------------------------
// fp32 -> bf16 conversion for x, Wq, Wk, Wv, Wo (8M elements, 8 per thread)
// ---------------------------------------------------------------------------
__global__ __launch_bounds__(256) void to_bf16_all(
    const float* __restrict__ x, const float* __restrict__ wq,
    const float* __restrict__ wk, const float* __restrict__ wv,
    const float* __restrict__ wo, unsigned short* __restrict__ xb,
    unsigned short* __restrict__ wqb, unsigned short* __restrict__ wkb,
    unsigned short* __restrict__ wvb, unsigned short* __restrict__ wob) {
  const size_t i = ((size_t)blockIdx.x * 256 + threadIdx.x) * 8;
  const float* src;
  unsigned short* dst;
  size_t off;
  if (i < 4194304)      { src = x;  dst = xb;  off = i; }
  else if (i < 5242880) { src = wq; dst = wqb; off = i - 4194304; }
  else if (i < 6291456) { src = wk; dst = wkb; off = i - 5242880; }
  else if (i < 7340032) { src = wv; dst = wvb; off = i - 6291456; }
  else                  { src = wo; dst = wob; off = i - 7340032; }
  f32x4 a = *(const f32x4*)(src + off);
  f32x4 b = *(const f32x4*)(src + off + 4);
  u16x8 o;
#pragma unroll
  for (int j = 0; j < 4; j++) { o[j] = f2bf(a[j]); o[4 + j] = f2bf(b[j]); }
  *(u16x8*)(dst + off) = o;
}

// ---------------------------------------------------------------------------
// 4-wave bf16 NT-GEMM core: acc += A[128 @ mbase] * W[128 @ nbase]^T.
// 4-buffer LDS, 2-tile-deep prefetch, counted vmcnt(8), ONE barrier per
// K-step (attn_v8's verified pattern): barrier sits between each wave's
// vmcnt-drain of tile kt and the reads of buf kt%4, so all waves' tile-kt
// loads have landed; earliest post-barrier staging targets (kt+3)%4 != kt%4.
// Halves barrier count vs the 2-barrier core (m233: sync overhead dominates).
// Linear LDS + XOR chunk swizzle (pre-swizzled source, swizzled read).
// ---------------------------------------------------------------------------
__device__ __forceinline__ void gemm_core(const unsigned short* __restrict__ A,
                                          const unsigned short* __restrict__ W,
                                          unsigned short (*Al)[128][32],
                                          unsigned short (*Bl)[128][32],
                                          int mbase, int nbase,
                                          f32x4 acc[4][4]) {
  const int tid  = threadIdx.x;
  const int lane = tid & 63;
  const int wid  = tid >> 6;
  const int wr   = wid >> 1, wc = wid & 1;
  const int g    = lane >> 4, lr = lane & 15;

  const int r0 = tid >> 2;                        // 0..63 staging row
  const int cg = (tid & 3) ^ ((tid >> 3) & 3);    // swizzled source chunk

  const unsigned short* Abase = A + (size_t)(mbase + r0) * D_MODEL + cg * 8;
  const unsigned short* Wbase = W + (size_t)(nbase + r0) * D_MODEL + cg * 8;
  char* ldsA0 = (char*)Al + wid * 1024;  // buffer stride 8192
  char* ldsB0 = (char*)Bl + wid * 1024;

#define STAGE_G(kt, buf)                                                   \
  {                                                                        \
    gload16(Abase + (kt) * 32, ldsA0 + (buf) * 8192);                      \
    gload16(Abase + (size_t)64 * D_MODEL + (kt) * 32,                      \
            ldsA0 + (buf) * 8192 + 4096);                                  \
    gload16(Wbase + (kt) * 32, ldsB0 + (buf) * 8192);                      \
    gload16(Wbase + (size_t)64 * D_MODEL + (kt) * 32,                      \
            ldsB0 + (buf) * 8192 + 4096);                                  \
  }

  // prologue: tiles 0,1 -> bufs 0,1 (4 gloads each)
  STAGE_G(0, 0);
  STAGE_G(1, 1);

  const int NKT = D_MODEL / 32;
  int cur = 0, nx2 = 2;
  for (int kt = 0; kt < NKT; ++kt) {
    if (kt + 2 < NKT) {  // prefetch tile kt+2 into buffer nx2
      STAGE_G(kt + 2, nx2);
      asm volatile("s_waitcnt vmcnt(8)" ::: "memory");  // tile kt landed
    } else if (kt + 1 < NKT) {
      asm volatile("s_waitcnt vmcnt(4)" ::: "memory");
    } else {
      asm volatile("s_waitcnt vmcnt(0)" ::: "memory");
    }
    __builtin_amdgcn_s_barrier();  // single barrier per K-step (4-buf safe)

    bf16x8 af[4], bfr[4];
#pragma unroll
    for (int i = 0; i < 4; i++) {
      const int ra = wr * 64 + i * 16 + lr;
      af[i] = *(const bf16x8*)&Al[cur][ra][(g ^ ((ra >> 1) & 3)) * 8];
      const int rb = wc * 64 + i * 16 + lr;
      bfr[i] = *(const bf16x8*)&Bl[cur][rb][(g ^ ((rb >> 1) & 3)) * 8];
    }
    __builtin_amdgcn_s_setprio(1);
#pragma unroll
    for (int i = 0; i < 4; i++)
#pragma unroll
      for (int j = 0; j < 4; j++)
        acc[i][j] = __builtin_amdgcn_mfma_f32_16x16x32_bf16(af[i], bfr[j],
                                                            acc[i][j], 0, 0, 0);
    __builtin_amdgcn_s_setprio(0);
    cur = (cur + 1) & 3;
    nx2 = (nx2 + 1) & 3;
  }
#undef STAGE_G
}

// ---------------------------------------------------------------------------
// Fused Q/K/V projection, 4-wave core + bijective XCD-chunked swizzle (T1).
// grid = 768 1-D blocks; w = (lin%8)*96 + lin/8.
// z=0 -> Q bf16 [M][D] PRE-SCALED by QSCALE; z=1 -> K; z=2 -> V transposed.
// ---------------------------------------------------------------------------
__global__ __launch_bounds__(256) void gemm_qkv(
    const unsigned short* __restrict__ xb, const unsigned short* __restrict__ wqb,
    const unsigned short* __restrict__ wkb, const unsigned short* __restrict__ wvb,
    unsigned short* __restrict__ qb, unsigned short* __restrict__ kb,
    unsigned short* __restrict__ vt) {
  __shared__ unsigned short Al[4][128][32];
  __shared__ unsigned short Bl[4][128][32];
  const int lin = blockIdx.x;
  const int w8  = (lin & 7) * 96 + (lin >> 3);   // bijective: 768 = 8*96
  const int xq  = w8 & 7;            // N tile (0..7)
  const int yq  = (w8 >> 3) & 31;    // M tile (0..31)
  const int z   = w8 >> 8;           // 0..2
  const unsigned short* W = (z == 0) ? wqb : (z == 1) ? wkb : wvb;
  unsigned short* dst = (z == 0) ? qb : (z == 1) ? kb : vt;
  const float sc = (z == 0) ? QSCALE : 1.0f;

  f32x4 acc[4][4];
#pragma unroll
  for (int i = 0; i < 4; i++)
#pragma unroll
    for (int j = 0; j < 4; j++) acc[i][j] = (f32x4){0.f, 0.f, 0.f, 0.f};

  const int mbase = yq * 128, nbase = xq * 128;
  gemm_core(xb, W, Al, Bl, mbase, nbase, acc);

  const int lane = threadIdx.x & 63, wid = threadIdx.x >> 6;
  const int wr = wid >> 1, wc = wid & 1, g = lane >> 4, lr = lane & 15;
#pragma unroll
  for (int i = 0; i < 4; i++) {
#pragma unroll
    for (int j = 0; j < 4; j++) {
      const int mg0 = mbase + wr * 64 + i * 16 + g * 4;  // + r
      const int ng  = nbase + wc * 64 + j * 16 + lr;
      if (z < 2) {
#pragma unroll
        for (int r = 0; r < 4; r++)
          dst[(size_t)(mg0 + r) * D_MODEL + ng] = f2bf(acc[i][j][r] * sc);
      } else {
        const int hh = ng >> 6, dd = ng & 63;
        const int bb = mg0 >> 11, ss = mg0 & 2047;  // mg0 mult of 4
        u16x4 pk;
#pragma unroll
        for (int r = 0; r < 4; r++) pk[r] = f2bf(acc[i][j][r]);
        *(u16x4*)&dst[((size_t)((bb * H_NUM + hh) * DH + dd)) * S_LEN + ss] = pk;
      }
    }
  }
}

// ---------------------------------------------------------------------------
// Output projection: out[M][D] fp32 = cx * Wo^T + bo (4-wave core + swizzle)
// grid = 256 1-D blocks; w = (lin%8)*32 + lin/8 (bijective: 256 = 8*32).
// ---------------------------------------------------------------------------
__global__ __launch_bounds__(256) void gemm_out(
    const unsigned short* __restrict__ cx, const unsigned short* __restrict__ wob,
    float* __restrict__ out, const float* __restrict__ bo) {
  __shared__ unsigned short Al[4][128][32];
  __shared__ unsigned short Bl[4][128][32];
  const int lin = blockIdx.x;
  const int w8  = (lin & 7) * 32 + (lin >> 3);
  const int xq  = w8 & 7;          // N tile
  const int yq  = w8 >> 3;         // M tile
  f32x4 acc[4][4];
#pragma unroll
  for (int i = 0; i < 4; i++)
#pragma unroll
    for (int j = 0; j < 4; j++) acc[i][j] = (f32x4){0.f, 0.f, 0.f, 0.f};

  const int mbase = yq * 128, nbase = xq * 128;
  gemm_core(cx, wob, Al, Bl, mbase, nbase, acc);

  const int lane = threadIdx.x & 63, wid = threadIdx.x >> 6;
  const int wr = wid >> 1, wc = wid & 1, g = lane >> 4, lr = lane & 15;
#pragma unroll
  for (int i = 0; i < 4; i++) {
#pragma unroll
    for (int j = 0; j < 4; j++) {
      const int mg0 = mbase + wr * 64 + i * 16 + g * 4;
      const int ng  = nbase + wc * 64 + j * 16 + lr;
      const float bv = bo[ng];
#pragma unroll
      for (int r = 0; r < 4; r++)
        out[(size_t)(mg0 + r) * D_MODEL + ng] = acc[i][j][r] + bv;
    }
  }
}

// ---------------------------------------------------------------------------
// Uniform <=8-tile chunking: qtile qi has T=2qi+2 kv-tiles, split into
// chunks[qi]=ceil(T/8) chunks. 40 entries/bh, longest-first -> 1280 blocks.
// part 0 writes unnormalized into cx (its natural slot); parts >=1 into
// Opart. qi<4 single-chunk -> normalized direct write. attn_combine merges.
// Encoding: qi | kt0<<8 | kt1<<16 | part<<24.
// ---------------------------------------------------------------------------
#define ENT(qi, k0, k1, p) ((unsigned)(qi) | ((unsigned)(k0) << 8) | \
                            ((unsigned)(k1) << 16) | ((unsigned)(p) << 24))
__device__ const unsigned att_sched[40] = {
    // len 8 (13)
    ENT(3, 0, 8, 0),   ENT(7, 0, 8, 0),   ENT(7, 8, 16, 1),
    ENT(10, 0, 8, 0),  ENT(11, 0, 8, 0),  ENT(11, 8, 16, 1),
    ENT(11, 16, 24, 2),ENT(14, 0, 8, 0),  ENT(14, 15, 23, 2),
    ENT(15, 0, 8, 0),  ENT(15, 8, 16, 1), ENT(15, 16, 24, 2),
    ENT(15, 24, 32, 3),
    // len 7 (14)
    ENT(6, 0, 7, 0),   ENT(6, 7, 14, 1),  ENT(9, 0, 7, 0),
    ENT(9, 7, 14, 1),  ENT(10, 8, 15, 1), ENT(10, 15, 22, 2),
    ENT(12, 0, 7, 0),  ENT(12, 13, 20, 2),ENT(13, 0, 7, 0),
    ENT(13, 7, 14, 1), ENT(13, 14, 21, 2),ENT(13, 21, 28, 3),
    ENT(14, 8, 15, 1), ENT(14, 23, 30, 3),
    // len 6 (9)
    ENT(2, 0, 6, 0),   ENT(5, 0, 6, 0),   ENT(5, 6, 12, 1),
    ENT(8, 0, 6, 0),   ENT(8, 6, 12, 1),  ENT(8, 12, 18, 2),
    ENT(9, 14, 20, 2), ENT(12, 7, 13, 1), ENT(12, 20, 26, 3),
    // len 5,4,2
    ENT(4, 0, 5, 0),   ENT(4, 5, 10, 1),  ENT(1, 0, 4, 0),
    ENT(0, 0, 2, 0),
};
__device__ const int att_chunks[16]   = {1,1,1,1, 2,2,2,2, 3,3,3,3, 4,4,4,4};
__device__ const int att_mlbase[16]   = {0,1,2,3, 4,6,8,10, 12,15,18,21,
                                         24,28,32,36};  // cumsum of chunks
__device__ const int att_opbase[16]   = {0,0,0,0, 0,1,2,3, 4,6,8,10,
                                         12,15,18,21};  // cumsum of chunks-1

// ---------------------------------------------------------------------------
// Causal flash attention v8d: 5-buffer K/V + one barrier per tile + 3-deep
// prefetch (counted vmcnt(12)); fixed softmax max m=0. LDS 80KB; 2 blocks/CU.
// Tl (18.4KB) overlays K bufs after an epilogue barrier.
// ---------------------------------------------------------------------------
__global__ __launch_bounds__(256) void attn_v8(
    const unsigned short* __restrict__ qb, const unsigned short* __restrict__ kb,
    const unsigned short* __restrict__ vt, unsigned short* __restrict__ cx,
    unsigned short* __restrict__ Opart, float* __restrict__ ml) {
  __shared__ alignas(16) char smem[81920];

  const int tid  = threadIdx.x;
  const int lane = tid & 63;
  const int w    = tid >> 6;
  const int hi   = lane >> 5;
  const int lq   = lane & 31;
  const int bid  = blockIdx.x;

  const unsigned ent = att_sched[bid >> 5];
  const int qi   = ent & 255;
  const int kt0  = (ent >> 8) & 255;
  const int kt1  = (ent >> 16) & 255;
  const int part = (ent >> 24) & 255;
  const int nch  = att_chunks[qi];
  const int bh   = bid & 31;
  const int b    = bh >> 4, h = bh & 15;

  const int qg0  = qi * 128 + w * 32;   // wave's q base within sequence
  const int tok0 = b * S_LEN + qg0;

  // staging: thread t -> row t>>3 (+32 for 2nd issue), chunk t&7 swizzled
  const int sr  = tid >> 3;
  const int scg = (tid & 7) ^ (sr & 7);
  const unsigned short* kbase =
      kb + (size_t)(b * S_LEN) * D_MODEL + h * DH + scg * 8;
  const unsigned short* vrow =
      vt + ((size_t)((b * H_NUM + h) * DH + sr)) * S_LEN + scg * 8;
  char* ldsK0 = smem + w * 1024;           // + buf*8192, buf 0..4
  char* ldsV0 = smem + 40960 + w * 1024;   // + buf*8192

  // Q fragments: B-operand, col q = lane&31, k = hi*8+j within slice ks
  bf16x8 qf[4];
  {
    const unsigned short* qrow =
        qb + (size_t)(tok0 + lq) * D_MODEL + h * DH + hi * 8;
#pragma unroll
    for (int ks = 0; ks < 4; ks++) qf[ks] = *(const bf16x8*)(qrow + ks * 16);
  }

  f32x16 ctx0, ctx1;
#pragma unroll
  for (int r = 0; r < 16; r++) { ctx0[r] = 0.f; ctx1[r] = 0.f; }
  float l_run = 0.f;

  const int ndiag = 2 * qi;

  // prologue: stage tiles kt0..kt0+2 -> bufs 0..2 (4 loads each, guarded)
#pragma unroll
  for (int p = 0; p < 3; p++) {
    if (kt0 + p < kt1) {
      const unsigned short* sK =
          kbase + (size_t)((kt0 + p) * 64 + sr) * D_MODEL;
      gload16(sK, ldsK0 + p * 8192);
      gload16(sK + (size_t)32 * D_MODEL, ldsK0 + p * 8192 + 4096);
      const unsigned short* sV = vrow + (kt0 + p) * 64;
      gload16(sV, ldsV0 + p * 8192);
      gload16(sV + (size_t)32 * S_LEN, ldsV0 + p * 8192 + 4096);
    }
  }

  int cur = 0, nx3 = 3;
  for (int kt = kt0; kt < kt1; ++kt) {
    if (kt + 3 < kt1) {  // prefetch tile kt+3 into buffer nx3
      const unsigned short* sK = kbase + (size_t)((kt + 3) * 64 + sr) * D_MODEL;
      gload16(sK, ldsK0 + nx3 * 8192);
      gload16(sK + (size_t)32 * D_MODEL, ldsK0 + nx3 * 8192 + 4096);
      const unsigned short* sV = vrow + (kt + 3) * 64;
      gload16(sV, ldsV0 + nx3 * 8192);
      gload16(sV + (size_t)32 * S_LEN, ldsV0 + nx3 * 8192 + 4096);
      asm volatile("s_waitcnt vmcnt(12)" ::: "memory");  // tile kt landed
    } else if (kt + 2 < kt1) {
      asm volatile("s_waitcnt vmcnt(8)" ::: "memory");
    } else if (kt + 1 < kt1) {
      asm volatile("s_waitcnt vmcnt(4)" ::: "memory");
    } else {
      asm volatile("s_waitcnt vmcnt(0)" ::: "memory");
    }
    __builtin_amdgcn_s_barrier();  // single barrier per tile (5-buf safe)

    const char* Kc = smem + cur * 8192;
    const char* Vc = smem + 40960 + cur * 8192;

    // ---- S^T = K Q^T : lane holds q=lq, 32 of 64 kv (partner l^32) ----
    f32x16 s0, s1;
#pragma unroll
    for (int r = 0; r < 16; r++) { s0[r] = 0.f; s1[r] = 0.f; }
    __builtin_amdgcn_s_setprio(1);
#pragma unroll
    for (int ks = 0; ks < 4; ks++) {
      const int c = ((ks * 2 + hi) ^ (lq & 7)) * 16;  // byte offset
      bf16x8 k0 = *(const bf16x8*)(Kc + lq * 128 + c);
      bf16x8 k1 = *(const bf16x8*)(Kc + (32 + lq) * 128 + c);
      s0 = __builtin_amdgcn_mfma_f32_32x32x16_bf16(k0, qf[ks], s0, 0, 0, 0);
      s1 = __builtin_amdgcn_mfma_f32_32x32x16_bf16(k1, qf[ks], s1, 0, 0, 0);
    }
    __builtin_amdgcn_s_setprio(0);

    // ---- causal mask (diagonal tiles only; uniform branch) ----
    if (kt >= ndiag) {
      const int relq = qg0 + lq - kt * 64 - 4 * hi;
#pragma unroll
      for (int r = 0; r < 16; r++) {
        const int ko = (r & 3) + 8 * (r >> 2);
        s0[r] = (ko > relq) ? -1e30f : s0[r];
        s1[r] = (ko + 32 > relq) ? -1e30f : s1[r];
      }
    }

    // ---- P = exp2(s) (fixed m=0; masked -> 0), pack + permlane, PV ----
    float lsAcc[4];
#pragma unroll
    for (int ks = 0; ks < 4; ks++) {
      float p[8];
#pragma unroll
      for (int j = 0; j < 8; j++) {
        const int r = (ks & 1) * 8 + j;
        const float sv = (ks < 2) ? s0[r] : s1[r];
        p[j] = fexp2(sv);
      }
      lsAcc[ks] = ((p[0] + p[1]) + (p[2] + p[3])) +
                  ((p[4] + p[5]) + (p[6] + p[7]));
      unsigned a0 = cvt_pk_bf16(p[0], p[1]);  // w01
      unsigned a1 = cvt_pk_bf16(p[4], p[5]);  // w45
      unsigned b0 = cvt_pk_bf16(p[2], p[3]);  // w23
      unsigned b1 = cvt_pk_bf16(p[6], p[7]);  // w67
      asm("v_permlane32_swap_b32 %0, %1" : "+v"(a0), "+v"(a1));
      asm("v_permlane32_swap_b32 %0, %1" : "+v"(b0), "+v"(b1));
      union { unsigned u[4]; bf16x8 v; } pw;
      pw.u[0] = a0;
      pw.u[1] = b0;
      pw.u[2] = a1;
      pw.u[3] = b1;
      const int c = ((ks * 2 + hi) ^ (lq & 7)) * 16;  // byte offset
      bf16x8 v0 = *(const bf16x8*)(Vc + lq * 128 + c);
      bf16x8 v1 = *(const bf16x8*)(Vc + (32 + lq) * 128 + c);
      __builtin_amdgcn_s_setprio(1);
      ctx0 = __builtin_amdgcn_mfma_f32_32x32x16_bf16(v0, pw.v, ctx0, 0, 0, 0);
      ctx1 = __builtin_amdgcn_mfma_f32_32x32x16_bf16(v1, pw.v, ctx1, 0, 0, 0);
      __builtin_amdgcn_s_setprio(0);
    }
    l_run += (lsAcc[0] + lsAcc[1]) + (lsAcc[2] + lsAcc[3]);
    cur = (cur == 4) ? 0 : cur + 1;
    nx3 = (nx3 == 4) ? 0 : nx3 + 1;
  }

  // ---- epilogue: barrier (Tl overlays K bufs), transpose, store ----
  __builtin_amdgcn_s_barrier();
  unsigned short (*Tl)[32][72] = (unsigned short (*)[32][72])smem;
  const float lfull = l_run + __shfl_xor(l_run, 32);
  const float inv   = (nch == 1) ? (1.0f / lfull) : 1.0f;
#pragma unroll
  for (int rp = 0; rp < 8; rp++) {
    const int r  = rp * 2;
    const int d0 = (r & 3) + 8 * (r >> 2) + 4 * hi;  // even; pair (d0, d0+1)
    *(unsigned*)&Tl[w][lq][d0] = cvt_pk_bf16(ctx0[r] * inv, ctx0[r + 1] * inv);
    *(unsigned*)&Tl[w][lq][32 + d0] =
        cvt_pk_bf16(ctx1[r] * inv, ctx1[r + 1] * inv);
  }
  asm volatile("s_waitcnt lgkmcnt(0)" ::: "memory");
  const int q2 = lane >> 1;  // q row within wave tile (0..31)
  unsigned short* dstp;
  if (nch == 1 || part == 0) {
    dstp = &cx[(size_t)(tok0 + q2) * D_MODEL + h * DH];
  } else {
    dstp = Opart + ((size_t)((att_opbase[qi] + part - 1) * 32 + bh) * 128 +
                    w * 32 + q2) * 64;
  }
#pragma unroll
  for (int i = 0; i < 4; i++) {
    const int ch = (lane & 1) * 4 + i;
    u16x8 vv = *(const u16x8*)&Tl[w][q2][ch * 8];
    *(u16x8*)&dstp[ch * 8] = vv;
  }
  if (nch > 1 && hi == 0) {  // per q-row (m=0, l) for combine
    float2 v2 = make_float2(0.0f, lfull);
    *(float2*)&ml[((size_t)((att_mlbase[qi] + part) * 32 + bh) * 128 +
                   w * 32 + lq) * 2] = v2;
  }
}

// ---------------------------------------------------------------------------
// Merge partials for qi>=4 (2..4 chunks). part 0 lives in cx (unnormalized);
// parts >=1 in Opart. 393216 threads: 8 per (qi, bh, row).
// ---------------------------------------------------------------------------
__global__ __launch_bounds__(256) void attn_combine(
    const unsigned short* __restrict__ Opart, const float* __restrict__ ml,
    unsigned short* __restrict__ cx) {
  const int gid = blockIdx.x * 256 + threadIdx.x;
  const int sub = gid & 7;
  const int row = (gid >> 3) & 127;
  const int bh  = (gid >> 10) & 31;
  const int qi  = 4 + (gid >> 15);      // 4..15
  const int nch = att_chunks[qi];
  const int b = bh >> 4, h = bh & 15;
  const int tok = b * S_LEN + qi * 128 + row;

  // gather l per part (m==0 fixed -> weights 1)
  float denom = 0.f;
#pragma unroll 4
  for (int p = 0; p < 4; p++) {
    if (p < nch) {
      const size_t mi =
          ((size_t)((att_mlbase[qi] + p) * 32 + bh) * 128 + row) * 2;
      denom += ml[mi + 1];
    }
  }
  const float inv = 1.0f / denom;

  float acc[8];
  {
    u16x8 a = *(const u16x8*)&cx[(size_t)tok * D_MODEL + h * DH + sub * 8];
#pragma unroll
    for (int j = 0; j < 8; j++) acc[j] = bf2f(a[j]);
  }
#pragma unroll 4
  for (int p = 1; p < 4; p++) {
    if (p < nch) {
      const unsigned short* src =
          Opart + ((size_t)((att_opbase[qi] + p - 1) * 32 + bh) * 128 + row) * 64;
      u16x8 a = *(const u16x8*)&src[sub * 8];
#pragma unroll
      for (int j = 0; j < 8; j++) acc[j] += bf2f(a[j]);
    }
  }
  u16x8 o;
#pragma unroll
  for (int j = 0; j < 8; j++) o[j] = f2bf(acc[j] * inv);
  *(u16x8*)&cx[(size_t)tok * D_MODEL + h * DH + sub * 8] = o;
}

// ---------------------------------------------------------------------------
extern "C" void kernel_launch(void* const* d_in, const int* in_sizes, int n_in,
                              void* d_out, int out_size, void* d_ws,
                              size_t ws_size, hipStream_t stream) {
  const float* x  = (const float*)d_in[0];
  const float* Wq = (const float*)d_in[1];
  const float* Wk = (const float*)d_in[2];
  const float* Wv = (const float*)d_in[3];
  const float* Wo = (const float*)d_in[4];
  const float* bo = (const float*)d_in[5];
  float* out = (float*)d_out;

  // workspace (bf16 elems): xb 4M | wqb,wkb,wvb,wob 1M | qb,kb,vt,cx 4M each
  // After gemm_qkv, [xb..wvb] (14 MB) is dead -> Opart (12.6 MB) + ml.
  unsigned short* xb  = (unsigned short*)d_ws;
  unsigned short* wqb = xb  + (size_t)M_TOT * D_MODEL;
  unsigned short* wkb = wqb + (size_t)D_MODEL * D_MODEL;
  unsigned short* wvb = wkb + (size_t)D_MODEL * D_MODEL;
  unsigned short* wob = wvb + (size_t)D_MODEL * D_MODEL;
  unsigned short* qb  = wob + (size_t)D_MODEL * D_MODEL;
  unsigned short* kb  = qb  + (size_t)M_TOT * D_MODEL;
  unsigned short* vt  = kb  + (size_t)M_TOT * D_MODEL;
  unsigned short* cx  = vt  + (size_t)M_TOT * D_MODEL;
  unsigned short* Opart = xb;                          // 768*8192 elems
  float*          ml    = (float*)(xb + (size_t)768 * 8192);

  to_bf16_all<<<4096, 256, 0, stream>>>(x, Wq, Wk, Wv, Wo, xb, wqb, wkb, wvb,
                                        wob);
  gemm_qkv<<<dim3(768), 256, 0, stream>>>(xb, wqb, wkb, wvb, qb, kb, vt);
  attn_v8<<<dim3(1280), 256, 0, stream>>>(qb, kb, vt, cx, Opart, ml);
  attn_combine<<<dim3(1536), 256, 0, stream>>>(Opart, ml, cx);
  gemm_out<<<dim3(256), 256, 0, stream>>>(cx, wob, out, bo);
}

// Round 21
// 109.403 us; speedup vs baseline: 1.0565x; 1.0565x over previous
//
#include <hip/hip_runtime.h>
#include <hip/hip_bf16.h>

// Problem constants (MultiHeadAttention, B=2, S=2048, D=1024, H=16)
#define B_SZ    2
#define S_LEN   2048
#define D_MODEL 1024
#define H_NUM   16
#define DH      64
#define M_TOT   (B_SZ * S_LEN)   // 4096 tokens

// scale = S^-0.5 (faithful bug) folded with log2(e) for exp2-domain softmax
#define QSCALE (0.022097086912079608f * 1.4426950408889634f)

typedef __attribute__((ext_vector_type(8)))  short          bf16x8;
typedef __attribute__((ext_vector_type(4)))  float          f32x4;
typedef __attribute__((ext_vector_type(16))) float          f32x16;
typedef __attribute__((ext_vector_type(8)))  unsigned short u16x8;
typedef __attribute__((ext_vector_type(4)))  unsigned short u16x4;

__device__ inline unsigned short f2bf(float f) {
  unsigned int u = __float_as_uint(f);
  u += 0x7fffu + ((u >> 16) & 1u);   // RNE (no NaN inputs here)
  return (unsigned short)(u >> 16);
}

__device__ inline float bf2f(unsigned short u) {
  return __uint_as_float(((unsigned)u) << 16);
}

__device__ inline float fexp2(float x) {
#if __has_builtin(__builtin_amdgcn_exp2f)
  return __builtin_amdgcn_exp2f(x);
#else
  return exp2f(x);
#endif
}

__device__ inline unsigned cvt_pk_bf16(float lo, float hi) {
  unsigned r;
  asm("v_cvt_pk_bf16_f32 %0, %1, %2" : "=v"(r) : "v"(lo), "v"(hi));
  return r;
}

// async global->LDS, 16B per lane. LDS dest = wave-uniform base + lane*16.
__device__ inline void gload16(const void* g, void* l) {
  __builtin_amdgcn_global_load_lds(
      (const __attribute__((address_space(1))) void*)g,
      (__attribute__((address_space(3))) void*)l, 16, 0, 0);
}

// ---------------------------------------------------------------------------
// fp32 -> bf16 conversion for x, Wq, Wk, Wv, Wo (8M elements, 8 per thread)
// ---------------------------------------------------------------------------
__global__ __launch_bounds__(256) void to_bf16_all(
    const float* __restrict__ x, const float* __restrict__ wq,
    const float* __restrict__ wk, const float* __restrict__ wv,
    const float* __restrict__ wo, unsigned short* __restrict__ xb,
    unsigned short* __restrict__ wqb, unsigned short* __restrict__ wkb,
    unsigned short* __restrict__ wvb, unsigned short* __restrict__ wob) {
  const size_t i = ((size_t)blockIdx.x * 256 + threadIdx.x) * 8;
  const float* src;
  unsigned short* dst;
  size_t off;
  if (i < 4194304)      { src = x;  dst = xb;  off = i; }
  else if (i < 5242880) { src = wq; dst = wqb; off = i - 4194304; }
  else if (i < 6291456) { src = wk; dst = wkb; off = i - 5242880; }
  else if (i < 7340032) { src = wv; dst = wvb; off = i - 6291456; }
  else                  { src = wo; dst = wob; off = i - 7340032; }
  f32x4 a = *(const f32x4*)(src + off);
  f32x4 b = *(const f32x4*)(src + off + 4);
  u16x8 o;
#pragma unroll
  for (int j = 0; j < 4; j++) { o[j] = f2bf(a[j]); o[4 + j] = f2bf(b[j]); }
  *(u16x8*)(dst + off) = o;
}

// ---------------------------------------------------------------------------
// 4-wave bf16 NT-GEMM core: acc += A[128 @ mbase] * W[128 @ nbase]^T.
// 3-buffer LDS, 2-tile-deep global_load_lds prefetch, counted vmcnt(8).
// Linear LDS + XOR chunk swizzle (pre-swizzled source, swizzled read).
// ---------------------------------------------------------------------------
__device__ __forceinline__ void gemm_core(const unsigned short* __restrict__ A,
                                          const unsigned short* __restrict__ W,
                                          unsigned short (*Al)[128][32],
                                          unsigned short (*Bl)[128][32],
                                          int mbase, int nbase,
                                          f32x4 acc[4][4]) {
  const int tid  = threadIdx.x;
  const int lane = tid & 63;
  const int wid  = tid >> 6;
  const int wr   = wid >> 1, wc = wid & 1;
  const int g    = lane >> 4, lr = lane & 15;

  const int r0 = tid >> 2;                        // 0..63 staging row
  const int cg = (tid & 3) ^ ((tid >> 3) & 3);    // swizzled source chunk

  const unsigned short* Abase = A + (size_t)(mbase + r0) * D_MODEL + cg * 8;
  const unsigned short* Wbase = W + (size_t)(nbase + r0) * D_MODEL + cg * 8;
  char* ldsA0 = (char*)Al + wid * 1024;  // buffer stride 8192
  char* ldsB0 = (char*)Bl + wid * 1024;

  // prologue: tiles 0,1 -> bufs 0,1
  gload16(Abase, ldsA0);
  gload16(Abase + (size_t)64 * D_MODEL, ldsA0 + 4096);
  gload16(Wbase, ldsB0);
  gload16(Wbase + (size_t)64 * D_MODEL, ldsB0 + 4096);
  gload16(Abase + 32, ldsA0 + 8192);
  gload16(Abase + (size_t)64 * D_MODEL + 32, ldsA0 + 8192 + 4096);
  gload16(Wbase + 32, ldsB0 + 8192);
  gload16(Wbase + (size_t)64 * D_MODEL + 32, ldsB0 + 8192 + 4096);

  const int NKT = D_MODEL / 32;
  int cur = 0, nx2 = 2;
  for (int kt = 0; kt < NKT; ++kt) {
    if (kt + 2 < NKT) {  // prefetch tile kt+2 into buffer nx2
      const unsigned short* As = Abase + (kt + 2) * 32;
      const unsigned short* Ws = Wbase + (kt + 2) * 32;
      char* la = ldsA0 + nx2 * 8192;
      char* lb = ldsB0 + nx2 * 8192;
      gload16(As, la);
      gload16(As + (size_t)64 * D_MODEL, la + 4096);
      gload16(Ws, lb);
      gload16(Ws + (size_t)64 * D_MODEL, lb + 4096);
      asm volatile("s_waitcnt vmcnt(8)" ::: "memory");  // tile kt landed
    } else if (kt + 1 < NKT) {
      asm volatile("s_waitcnt vmcnt(4)" ::: "memory");
    } else {
      asm volatile("s_waitcnt vmcnt(0)" ::: "memory");
    }
    __builtin_amdgcn_s_barrier();

    bf16x8 af[4], bfr[4];
#pragma unroll
    for (int i = 0; i < 4; i++) {
      const int ra = wr * 64 + i * 16 + lr;
      af[i] = *(const bf16x8*)&Al[cur][ra][(g ^ ((ra >> 1) & 3)) * 8];
      const int rb = wc * 64 + i * 16 + lr;
      bfr[i] = *(const bf16x8*)&Bl[cur][rb][(g ^ ((rb >> 1) & 3)) * 8];
    }
    __builtin_amdgcn_s_setprio(1);
#pragma unroll
    for (int i = 0; i < 4; i++)
#pragma unroll
      for (int j = 0; j < 4; j++)
        acc[i][j] = __builtin_amdgcn_mfma_f32_16x16x32_bf16(af[i], bfr[j],
                                                            acc[i][j], 0, 0, 0);
    __builtin_amdgcn_s_setprio(0);
    asm volatile("" ::: "memory");
    __builtin_amdgcn_s_barrier();  // buf[cur] now free for re-staging
    cur = (cur == 2) ? 0 : cur + 1;
    nx2 = (nx2 == 2) ? 0 : nx2 + 1;
  }
}

// ---------------------------------------------------------------------------
// Fused Q/K/V projection, 4-wave core + bijective XCD-chunked swizzle (T1).
// grid = 768 1-D blocks; w = (lin%8)*96 + lin/8 gives each XCD a contiguous
// work chunk (same-A-panel blocks colocate -> A slice L2-resident).
// z=0 -> Q bf16 [M][D] PRE-SCALED by QSCALE; z=1 -> K; z=2 -> V transposed.
// ---------------------------------------------------------------------------
__global__ __launch_bounds__(256) void gemm_qkv(
    const unsigned short* __restrict__ xb, const unsigned short* __restrict__ wqb,
    const unsigned short* __restrict__ wkb, const unsigned short* __restrict__ wvb,
    unsigned short* __restrict__ qb, unsigned short* __restrict__ kb,
    unsigned short* __restrict__ vt) {
  __shared__ unsigned short Al[3][128][32];
  __shared__ unsigned short Bl[3][128][32];
  const int lin = blockIdx.x;
  const int w8  = (lin & 7) * 96 + (lin >> 3);   // bijective: 768 = 8*96
  const int xq  = w8 & 7;            // N tile (0..7)
  const int yq  = (w8 >> 3) & 31;    // M tile (0..31)
  const int z   = w8 >> 8;           // 0..2
  const unsigned short* W = (z == 0) ? wqb : (z == 1) ? wkb : wvb;
  unsigned short* dst = (z == 0) ? qb : (z == 1) ? kb : vt;
  const float sc = (z == 0) ? QSCALE : 1.0f;

  f32x4 acc[4][4];
#pragma unroll
  for (int i = 0; i < 4; i++)
#pragma unroll
    for (int j = 0; j < 4; j++) acc[i][j] = (f32x4){0.f, 0.f, 0.f, 0.f};

  const int mbase = yq * 128, nbase = xq * 128;
  gemm_core(xb, W, Al, Bl, mbase, nbase, acc);

  const int lane = threadIdx.x & 63, wid = threadIdx.x >> 6;
  const int wr = wid >> 1, wc = wid & 1, g = lane >> 4, lr = lane & 15;
#pragma unroll
  for (int i = 0; i < 4; i++) {
#pragma unroll
    for (int j = 0; j < 4; j++) {
      const int mg0 = mbase + wr * 64 + i * 16 + g * 4;  // + r
      const int ng  = nbase + wc * 64 + j * 16 + lr;
      if (z < 2) {
#pragma unroll
        for (int r = 0; r < 4; r++)
          dst[(size_t)(mg0 + r) * D_MODEL + ng] = f2bf(acc[i][j][r] * sc);
      } else {
        const int hh = ng >> 6, dd = ng & 63;
        const int bb = mg0 >> 11, ss = mg0 & 2047;  // mg0 mult of 4
        u16x4 pk;
#pragma unroll
        for (int r = 0; r < 4; r++) pk[r] = f2bf(acc[i][j][r]);
        *(u16x4*)&dst[((size_t)((bb * H_NUM + hh) * DH + dd)) * S_LEN + ss] = pk;
      }
    }
  }
}

// ---------------------------------------------------------------------------
// Output projection: out[M][D] fp32 = cx * Wo^T + bo (4-wave core + swizzle)
// grid = 256 1-D blocks; w = (lin%8)*32 + lin/8 (bijective: 256 = 8*32).
// ---------------------------------------------------------------------------
__global__ __launch_bounds__(256) void gemm_out(
    const unsigned short* __restrict__ cx, const unsigned short* __restrict__ wob,
    float* __restrict__ out, const float* __restrict__ bo) {
  __shared__ unsigned short Al[3][128][32];
  __shared__ unsigned short Bl[3][128][32];
  const int lin = blockIdx.x;
  const int w8  = (lin & 7) * 32 + (lin >> 3);
  const int xq  = w8 & 7;          // N tile
  const int yq  = w8 >> 3;         // M tile
  f32x4 acc[4][4];
#pragma unroll
  for (int i = 0; i < 4; i++)
#pragma unroll
    for (int j = 0; j < 4; j++) acc[i][j] = (f32x4){0.f, 0.f, 0.f, 0.f};

  const int mbase = yq * 128, nbase = xq * 128;
  gemm_core(cx, wob, Al, Bl, mbase, nbase, acc);

  const int lane = threadIdx.x & 63, wid = threadIdx.x >> 6;
  const int wr = wid >> 1, wc = wid & 1, g = lane >> 4, lr = lane & 15;
#pragma unroll
  for (int i = 0; i < 4; i++) {
#pragma unroll
    for (int j = 0; j < 4; j++) {
      const int mg0 = mbase + wr * 64 + i * 16 + g * 4;
      const int ng  = nbase + wc * 64 + j * 16 + lr;
      const float bv = bo[ng];
#pragma unroll
      for (int r = 0; r < 4; r++)
        out[(size_t)(mg0 + r) * D_MODEL + ng] = acc[i][j][r] + bv;
    }
  }
}

// ---------------------------------------------------------------------------
// Uniform <=8-tile chunking: qtile qi has T=2qi+2 kv-tiles, split into
// chunks[qi]=ceil(T/8) chunks. 40 entries/bh, longest-first -> 1280 blocks.
// part 0 writes unnormalized into cx (its natural slot); parts >=1 into
// Opart. qi<4 single-chunk -> normalized direct write. attn_combine merges.
// Encoding: qi | kt0<<8 | kt1<<16 | part<<24.
// ---------------------------------------------------------------------------
#define ENT(qi, k0, k1, p) ((unsigned)(qi) | ((unsigned)(k0) << 8) | \
                            ((unsigned)(k1) << 16) | ((unsigned)(p) << 24))
__device__ const unsigned att_sched[40] = {
    // len 8 (13)
    ENT(3, 0, 8, 0),   ENT(7, 0, 8, 0),   ENT(7, 8, 16, 1),
    ENT(10, 0, 8, 0),  ENT(11, 0, 8, 0),  ENT(11, 8, 16, 1),
    ENT(11, 16, 24, 2),ENT(14, 0, 8, 0),  ENT(14, 15, 23, 2),
    ENT(15, 0, 8, 0),  ENT(15, 8, 16, 1), ENT(15, 16, 24, 2),
    ENT(15, 24, 32, 3),
    // len 7 (14)
    ENT(6, 0, 7, 0),   ENT(6, 7, 14, 1),  ENT(9, 0, 7, 0),
    ENT(9, 7, 14, 1),  ENT(10, 8, 15, 1), ENT(10, 15, 22, 2),
    ENT(12, 0, 7, 0),  ENT(12, 13, 20, 2),ENT(13, 0, 7, 0),
    ENT(13, 7, 14, 1), ENT(13, 14, 21, 2),ENT(13, 21, 28, 3),
    ENT(14, 8, 15, 1), ENT(14, 23, 30, 3),
    // len 6 (9)
    ENT(2, 0, 6, 0),   ENT(5, 0, 6, 0),   ENT(5, 6, 12, 1),
    ENT(8, 0, 6, 0),   ENT(8, 6, 12, 1),  ENT(8, 12, 18, 2),
    ENT(9, 14, 20, 2), ENT(12, 7, 13, 1), ENT(12, 20, 26, 3),
    // len 5,4,2
    ENT(4, 0, 5, 0),   ENT(4, 5, 10, 1),  ENT(1, 0, 4, 0),
    ENT(0, 0, 2, 0),
};
__device__ const int att_chunks[16]   = {1,1,1,1, 2,2,2,2, 3,3,3,3, 4,4,4,4};
__device__ const int att_mlbase[16]   = {0,1,2,3, 4,6,8,10, 12,15,18,21,
                                         24,28,32,36};  // cumsum of chunks
__device__ const int att_opbase[16]   = {0,0,0,0, 0,1,2,3, 4,6,8,10,
                                         12,15,18,21};  // cumsum of chunks-1

// ---------------------------------------------------------------------------
// Causal flash attention v8: 4-buffer K/V + one barrier per tile; fixed
// softmax max m=0 (bug-scaled scores; per-row factor cancels in l-norm).
// LDS 64KB: K bufs [0,32K), V bufs [32K,64K); Tl overlays K after barrier.
// ---------------------------------------------------------------------------
__global__ __launch_bounds__(256) void attn_v8(
    const unsigned short* __restrict__ qb, const unsigned short* __restrict__ kb,
    const unsigned short* __restrict__ vt, unsigned short* __restrict__ cx,
    unsigned short* __restrict__ Opart, float* __restrict__ ml) {
  __shared__ alignas(16) char smem[65536];

  const int tid  = threadIdx.x;
  const int lane = tid & 63;
  const int w    = tid >> 6;
  const int hi   = lane >> 5;
  const int lq   = lane & 31;
  const int bid  = blockIdx.x;

  const unsigned ent = att_sched[bid >> 5];
  const int qi   = ent & 255;
  const int kt0  = (ent >> 8) & 255;
  const int kt1  = (ent >> 16) & 255;
  const int part = (ent >> 24) & 255;
  const int nch  = att_chunks[qi];
  const int bh   = bid & 31;
  const int b    = bh >> 4, h = bh & 15;

  const int qg0  = qi * 128 + w * 32;   // wave's q base within sequence
  const int tok0 = b * S_LEN + qg0;

  // staging: thread t -> row t>>3 (+32 for 2nd issue), chunk t&7 swizzled
  const int sr  = tid >> 3;
  const int scg = (tid & 7) ^ (sr & 7);
  const unsigned short* kbase =
      kb + (size_t)(b * S_LEN) * D_MODEL + h * DH + scg * 8;
  const unsigned short* vrow =
      vt + ((size_t)((b * H_NUM + h) * DH + sr)) * S_LEN + scg * 8;
  char* ldsK0 = smem + w * 1024;           // + buf*8192, buf 0..3
  char* ldsV0 = smem + 32768 + w * 1024;   // + buf*8192

  // Q fragments: B-operand, col q = lane&31, k = hi*8+j within slice ks
  bf16x8 qf[4];
  {
    const unsigned short* qrow =
        qb + (size_t)(tok0 + lq) * D_MODEL + h * DH + hi * 8;
#pragma unroll
    for (int ks = 0; ks < 4; ks++) qf[ks] = *(const bf16x8*)(qrow + ks * 16);
  }

  f32x16 ctx0, ctx1;
#pragma unroll
  for (int r = 0; r < 16; r++) { ctx0[r] = 0.f; ctx1[r] = 0.f; }
  float l_run = 0.f;

  const int ndiag = 2 * qi;

  // prologue: stage tiles kt0 -> buf0, kt0+1 -> buf1 (4 loads each)
  {
    const unsigned short* sK = kbase + (size_t)(kt0 * 64 + sr) * D_MODEL;
    gload16(sK, ldsK0);
    gload16(sK + (size_t)32 * D_MODEL, ldsK0 + 4096);
    const unsigned short* sV = vrow + kt0 * 64;
    gload16(sV, ldsV0);
    gload16(sV + (size_t)32 * S_LEN, ldsV0 + 4096);
    if (kt0 + 1 < kt1) {
      const unsigned short* sK1 = sK + (size_t)64 * D_MODEL;
      gload16(sK1, ldsK0 + 8192);
      gload16(sK1 + (size_t)32 * D_MODEL, ldsK0 + 8192 + 4096);
      const unsigned short* sV1 = sV + 64;
      gload16(sV1, ldsV0 + 8192);
      gload16(sV1 + (size_t)32 * S_LEN, ldsV0 + 8192 + 4096);
    }
  }

  int cur = 0, nx2 = 2;
  for (int kt = kt0; kt < kt1; ++kt) {
    if (kt + 2 < kt1) {  // prefetch tile kt+2 into buffer nx2
      const unsigned short* sK = kbase + (size_t)((kt + 2) * 64 + sr) * D_MODEL;
      gload16(sK, ldsK0 + nx2 * 8192);
      gload16(sK + (size_t)32 * D_MODEL, ldsK0 + nx2 * 8192 + 4096);
      const unsigned short* sV = vrow + (kt + 2) * 64;
      gload16(sV, ldsV0 + nx2 * 8192);
      gload16(sV + (size_t)32 * S_LEN, ldsV0 + nx2 * 8192 + 4096);
      asm volatile("s_waitcnt vmcnt(8)" ::: "memory");  // tile kt landed
    } else if (kt + 1 < kt1) {
      asm volatile("s_waitcnt vmcnt(4)" ::: "memory");
    } else {
      asm volatile("s_waitcnt vmcnt(0)" ::: "memory");
    }
    __builtin_amdgcn_s_barrier();  // single barrier per tile (4-buf safe)

    const char* Kc = smem + cur * 8192;
    const char* Vc = smem + 32768 + cur * 8192;

    // ---- S^T = K Q^T : lane holds q=lq, 32 of 64 kv (partner l^32) ----
    f32x16 s0, s1;
#pragma unroll
    for (int r = 0; r < 16; r++) { s0[r] = 0.f; s1[r] = 0.f; }
    __builtin_amdgcn_s_setprio(1);
#pragma unroll
    for (int ks = 0; ks < 4; ks++) {
      const int c = ((ks * 2 + hi) ^ (lq & 7)) * 16;  // byte offset
      bf16x8 k0 = *(const bf16x8*)(Kc + lq * 128 + c);
      bf16x8 k1 = *(const bf16x8*)(Kc + (32 + lq) * 128 + c);
      s0 = __builtin_amdgcn_mfma_f32_32x32x16_bf16(k0, qf[ks], s0, 0, 0, 0);
      s1 = __builtin_amdgcn_mfma_f32_32x32x16_bf16(k1, qf[ks], s1, 0, 0, 0);
    }
    __builtin_amdgcn_s_setprio(0);

    // ---- causal mask (diagonal tiles only; uniform branch) ----
    if (kt >= ndiag) {
      const int relq = qg0 + lq - kt * 64 - 4 * hi;
#pragma unroll
      for (int r = 0; r < 16; r++) {
        const int ko = (r & 3) + 8 * (r >> 2);
        s0[r] = (ko > relq) ? -1e30f : s0[r];
        s1[r] = (ko + 32 > relq) ? -1e30f : s1[r];
      }
    }

    // ---- P = exp2(s) (fixed m=0; masked -> 0), pack + permlane, PV ----
    float lsAcc[4];
#pragma unroll
    for (int ks = 0; ks < 4; ks++) {
      float p[8];
#pragma unroll
      for (int j = 0; j < 8; j++) {
        const int r = (ks & 1) * 8 + j;
        const float sv = (ks < 2) ? s0[r] : s1[r];
        p[j] = fexp2(sv);
      }
      lsAcc[ks] = ((p[0] + p[1]) + (p[2] + p[3])) +
                  ((p[4] + p[5]) + (p[6] + p[7]));
      // pack pairs; permlane32_swap: (a,b) -> a'={a_lo,b_lo}, b'={a_hi,b_hi}
      unsigned a0 = cvt_pk_bf16(p[0], p[1]);  // w01
      unsigned a1 = cvt_pk_bf16(p[4], p[5]);  // w45
      unsigned b0 = cvt_pk_bf16(p[2], p[3]);  // w23
      unsigned b1 = cvt_pk_bf16(p[6], p[7]);  // w67
      asm("v_permlane32_swap_b32 %0, %1" : "+v"(a0), "+v"(a1));
      asm("v_permlane32_swap_b32 %0, %1" : "+v"(b0), "+v"(b1));
      union { unsigned u[4]; bf16x8 v; } pw;
      pw.u[0] = a0;  // lo: w01          | hi: partner w45
      pw.u[1] = b0;  // lo: w23          | hi: partner w67
      pw.u[2] = a1;  // lo: partner w01  | hi: w45
      pw.u[3] = b1;  // lo: partner w23  | hi: w67
      const int c = ((ks * 2 + hi) ^ (lq & 7)) * 16;  // byte offset
      bf16x8 v0 = *(const bf16x8*)(Vc + lq * 128 + c);
      bf16x8 v1 = *(const bf16x8*)(Vc + (32 + lq) * 128 + c);
      __builtin_amdgcn_s_setprio(1);
      ctx0 = __builtin_amdgcn_mfma_f32_32x32x16_bf16(v0, pw.v, ctx0, 0, 0, 0);
      ctx1 = __builtin_amdgcn_mfma_f32_32x32x16_bf16(v1, pw.v, ctx1, 0, 0, 0);
      __builtin_amdgcn_s_setprio(0);
    }
    l_run += (lsAcc[0] + lsAcc[1]) + (lsAcc[2] + lsAcc[3]);
    cur = (cur + 1) & 3;
    nx2 = (nx2 + 1) & 3;
  }

  // ---- epilogue: barrier (Tl overlays K bufs), transpose, store ----
  __builtin_amdgcn_s_barrier();
  unsigned short (*Tl)[32][72] = (unsigned short (*)[32][72])smem;
  const float lfull = l_run + __shfl_xor(l_run, 32);
  const float inv   = (nch == 1) ? (1.0f / lfull) : 1.0f;
#pragma unroll
  for (int rp = 0; rp < 8; rp++) {
    const int r  = rp * 2;
    const int d0 = (r & 3) + 8 * (r >> 2) + 4 * hi;  // even; pair (d0, d0+1)
    *(unsigned*)&Tl[w][lq][d0] = cvt_pk_bf16(ctx0[r] * inv, ctx0[r + 1] * inv);
    *(unsigned*)&Tl[w][lq][32 + d0] =
        cvt_pk_bf16(ctx1[r] * inv, ctx1[r + 1] * inv);
  }
  asm volatile("s_waitcnt lgkmcnt(0)" ::: "memory");
  const int q2 = lane >> 1;  // q row within wave tile (0..31)
  unsigned short* dstp;
  if (nch == 1 || part == 0) {
    dstp = &cx[(size_t)(tok0 + q2) * D_MODEL + h * DH];
  } else {
    dstp = Opart + ((size_t)((att_opbase[qi] + part - 1) * 32 + bh) * 128 +
                    w * 32 + q2) * 64;
  }
#pragma unroll
  for (int i = 0; i < 4; i++) {
    const int ch = (lane & 1) * 4 + i;
    u16x8 vv = *(const u16x8*)&Tl[w][q2][ch * 8];
    *(u16x8*)&dstp[ch * 8] = vv;
  }
  if (nch > 1 && hi == 0) {  // per q-row (m=0, l) for combine
    float2 v2 = make_float2(0.0f, lfull);
    *(float2*)&ml[((size_t)((att_mlbase[qi] + part) * 32 + bh) * 128 +
                   w * 32 + lq) * 2] = v2;
  }
}

// ---------------------------------------------------------------------------
// Merge partials for qi>=4 (2..4 chunks). part 0 lives in cx (unnormalized);
// parts >=1 in Opart. 393216 threads: 8 per (qi, bh, row).
// ---------------------------------------------------------------------------
__global__ __launch_bounds__(256) void attn_combine(
    const unsigned short* __restrict__ Opart, const float* __restrict__ ml,
    unsigned short* __restrict__ cx) {
  const int gid = blockIdx.x * 256 + threadIdx.x;
  const int sub = gid & 7;
  const int row = (gid >> 3) & 127;
  const int bh  = (gid >> 10) & 31;
  const int qi  = 4 + (gid >> 15);      // 4..15
  const int nch = att_chunks[qi];
  const int b = bh >> 4, h = bh & 15;
  const int tok = b * S_LEN + qi * 128 + row;

  // gather l per part (m==0 fixed -> weights 1)
  float denom = 0.f;
#pragma unroll 4
  for (int p = 0; p < 4; p++) {
    if (p < nch) {
      const size_t mi =
          ((size_t)((att_mlbase[qi] + p) * 32 + bh) * 128 + row) * 2;
      denom += ml[mi + 1];
    }
  }
  const float inv = 1.0f / denom;

  float acc[8];
  {
    u16x8 a = *(const u16x8*)&cx[(size_t)tok * D_MODEL + h * DH + sub * 8];
#pragma unroll
    for (int j = 0; j < 8; j++) acc[j] = bf2f(a[j]);
  }
#pragma unroll 4
  for (int p = 1; p < 4; p++) {
    if (p < nch) {
      const unsigned short* src =
          Opart + ((size_t)((att_opbase[qi] + p - 1) * 32 + bh) * 128 + row) * 64;
      u16x8 a = *(const u16x8*)&src[sub * 8];
#pragma unroll
      for (int j = 0; j < 8; j++) acc[j] += bf2f(a[j]);
    }
  }
  u16x8 o;
#pragma unroll
  for (int j = 0; j < 8; j++) o[j] = f2bf(acc[j] * inv);
  *(u16x8*)&cx[(size_t)tok * D_MODEL + h * DH + sub * 8] = o;
}

// ---------------------------------------------------------------------------
extern "C" void kernel_launch(void* const* d_in, const int* in_sizes, int n_in,
                              void* d_out, int out_size, void* d_ws,
                              size_t ws_size, hipStream_t stream) {
  const float* x  = (const float*)d_in[0];
  const float* Wq = (const float*)d_in[1];
  const float* Wk = (const float*)d_in[2];
  const float* Wv = (const float*)d_in[3];
  const float* Wo = (const float*)d_in[4];
  const float* bo = (const float*)d_in[5];
  float* out = (float*)d_out;

  // workspace (bf16 elems): xb 4M | wqb,wkb,wvb,wob 1M | qb,kb,vt,cx 4M each
  // After gemm_qkv, [xb..wvb] (14 MB) is dead -> Opart (12.6 MB) + ml.
  unsigned short* xb  = (unsigned short*)d_ws;
  unsigned short* wqb = xb  + (size_t)M_TOT * D_MODEL;
  unsigned short* wkb = wqb + (size_t)D_MODEL * D_MODEL;
  unsigned short* wvb = wkb + (size_t)D_MODEL * D_MODEL;
  unsigned short* wob = wvb + (size_t)D_MODEL * D_MODEL;
  unsigned short* qb  = wob + (size_t)D_MODEL * D_MODEL;
  unsigned short* kb  = qb  + (size_t)M_TOT * D_MODEL;
  unsigned short* vt  = kb  + (size_t)M_TOT * D_MODEL;
  unsigned short* cx  = vt  + (size_t)M_TOT * D_MODEL;
  unsigned short* Opart = xb;                          // 768*8192 elems
  float*          ml    = (float*)(xb + (size_t)768 * 8192);

  to_bf16_all<<<4096, 256, 0, stream>>>(x, Wq, Wk, Wv, Wo, xb, wqb, wkb, wvb,
                                        wob);
  gemm_qkv<<<dim3(768), 256, 0, stream>>>(xb, wqb, wkb, wvb, qb, kb, vt);
  attn_v8<<<dim3(1280), 256, 0, stream>>>(qb, kb, vt, cx, Opart, ml);
  attn_combine<<<dim3(1536), 256, 0, stream>>>(Opart, ml, cx);
  gemm_out<<<dim3(256), 256, 0, stream>>>(cx, wob, out, bo);
}